// Round 8
// baseline (248.823 us; speedup 1.0000x reference)
//
#include <hip/hip_runtime.h>
#include <cstdint>

#define NHEAD 16
#define DHEAD 64
#define SEQ   2048
#define DMODEL 1024
#define MTOT  4096
#define NQKV  3072

typedef __bf16 bf16x8 __attribute__((ext_vector_type(8)));
typedef short  s16x4  __attribute__((ext_vector_type(4)));
typedef float  f32x4  __attribute__((ext_vector_type(4)));

__device__ __forceinline__ unsigned short f2bf(float f) {
  union { float f; unsigned u; } v; v.f = f;
  unsigned r = v.u + 0x7fffu + ((v.u >> 16) & 1u);
  return (unsigned short)(r >> 16);
}

// async global->LDS, 16B per lane. LDS dest must be wave-uniform base + lane*16.
__device__ __forceinline__ void gl_lds16(const void* g, void* l) {
  __builtin_amdgcn_global_load_lds(
      reinterpret_cast<const __attribute__((address_space(1))) unsigned int*>(
          reinterpret_cast<uintptr_t>(g)),
      reinterpret_cast<__attribute__((address_space(3))) unsigned int*>(
          reinterpret_cast<uintptr_t>(l)),
      16, 0, 0);
}

#if __has_builtin(__builtin_amdgcn_mfma_f32_16x16x16bf16_1k)
#define MFMA_PV(a, b, c) __builtin_amdgcn_mfma_f32_16x16x16bf16_1k(a, b, c, 0, 0, 0)
#else
__device__ __forceinline__ f32x4 mfma_pv_asm(s16x4 a, s16x4 b, f32x4 c) {
  f32x4 d;
  asm volatile("v_mfma_f32_16x16x16_bf16 %0, %1, %2, %3"
               : "=v"(d) : "v"(a), "v"(b), "v"(c));
  return d;
}
#define MFMA_PV(a, b, c) mfma_pv_asm(a, b, c)
#endif

// Q pre-scale: softmax scale folded into Q at GEMM1 (0.125 * log2(e)).
#define QSCALE 0.18033688011112042f

// ---------------- merged pre-pass: fp32->bf16 input cvt + both weight transposes ----
__global__ void k_prepass(const float* __restrict__ x, unsigned short* __restrict__ y,
                          const float* __restrict__ W0, unsigned short* __restrict__ T0,
                          const float* __restrict__ W1, unsigned short* __restrict__ T1) {
  __shared__ unsigned short t[32][33];
  const int bid = blockIdx.x;
  if (bid < 4096) {
    const int i = bid * 256 + threadIdx.x;
    float4 v = reinterpret_cast<const float4*>(x)[i];
    ushort4 o;
    o.x = f2bf(v.x); o.y = f2bf(v.y); o.z = f2bf(v.z); o.w = f2bf(v.w);
    reinterpret_cast<ushort4*>(y)[i] = o;
  } else {
    const int b2 = bid - 4096;
    const int bx = b2 & 127;           // 0..127 (96 for W_qkv, 32 for W_out)
    const int by = b2 >> 7;            // 0..31  (K/32 tiles)
    const float* W = (bx < 96) ? W0 : W1;
    unsigned short* WT = (bx < 96) ? T0 : T1;
    const int N = (bx < 96) ? 3072 : 1024;
    const int n0 = ((bx < 96) ? bx : (bx - 96)) * 32;
    const int k0 = by * 32;
    const int tx = threadIdx.x & 31, ty = threadIdx.x >> 5;
    for (int i = ty; i < 32; i += 8)
      t[i][tx] = f2bf(W[(size_t)(k0 + i) * N + n0 + tx]);
    __syncthreads();
    for (int i = ty; i < 32; i += 8)
      WT[(size_t)(n0 + i) * 1024 + k0 + tx] = t[tx][i];
  }
}

// ---------------- GEMM1: double-buffered LDS, 1 barrier/iter, BK=32 ----------------
// R0-proven main loop; R3-proven fused V^T epilogue; QSCALE kept; no XCD swizzle.
__global__ __launch_bounds__(256, 3) void k_gemm_qkv(
    const unsigned short* __restrict__ A, const unsigned short* __restrict__ Bt,
    const float* __restrict__ bias, float* __restrict__ outbase,
    unsigned short* __restrict__ qbf, unsigned short* __restrict__ kbf,
    unsigned short* __restrict__ vtbf) {
  __shared__ __attribute__((aligned(16))) unsigned short As[2][128 * 32];
  __shared__ __attribute__((aligned(16))) unsigned short Bs[2][128 * 32];
  const int tid = threadIdx.x, lane = tid & 63;
  const int w = tid >> 6, wm = w >> 1, wn = w & 1;
  const int c = lane & 15, q = lane >> 4;
  const int kc = (c & 3) ^ ((c >> 2) & 3);        // frag-read swizzle key
  const int bm = blockIdx.x * 128, bn = blockIdx.y * 128;
  const int srow = tid >> 2;
  const int skey = (srow & 3) ^ ((srow >> 2) & 3);
  const int scolsw = (((tid & 3) ^ skey) << 3);   // swizzled global source column
  const unsigned short* Ag = A + (size_t)(bm + srow) * DMODEL + scolsw;
  const unsigned short* Bg = Bt + (size_t)(bn + srow) * DMODEL + scolsw;
  f32x4 acc[4][4] = {};

  // stage tile 0 into buf 0
  gl_lds16(Ag, As[0] + tid * 8);
  gl_lds16(Ag + (size_t)64 * DMODEL, As[0] + 2048 + tid * 8);
  gl_lds16(Bg, Bs[0] + tid * 8);
  gl_lds16(Bg + (size_t)64 * DMODEL, Bs[0] + 2048 + tid * 8);

  for (int kt = 0; kt < 32; ++kt) {
    const int cur = kt & 1;
    __syncthreads();  // drains loads issued LAST iter (fully latency-hidden)
    if (kt < 31) {    // prefetch tile kt+1 into the other buffer
      const int k0 = (kt + 1) * 32;
      gl_lds16(Ag + k0, As[cur ^ 1] + tid * 8);
      gl_lds16(Ag + k0 + (size_t)64 * DMODEL, As[cur ^ 1] + 2048 + tid * 8);
      gl_lds16(Bg + k0, Bs[cur ^ 1] + tid * 8);
      gl_lds16(Bg + k0 + (size_t)64 * DMODEL, Bs[cur ^ 1] + 2048 + tid * 8);
    }
    const int ch = (q ^ kc) << 3;
    bf16x8 af[4], bfr[4];
#pragma unroll
    for (int i = 0; i < 4; ++i)
      af[i] = *reinterpret_cast<const bf16x8*>(As[cur] + (wm * 64 + i * 16 + c) * 32 + ch);
#pragma unroll
    for (int j = 0; j < 4; ++j)
      bfr[j] = *reinterpret_cast<const bf16x8*>(Bs[cur] + (wn * 64 + j * 16 + c) * 32 + ch);
#pragma unroll
    for (int i = 0; i < 4; ++i)
#pragma unroll
      for (int j = 0; j < 4; ++j)
        acc[i][j] = __builtin_amdgcn_mfma_f32_16x16x32_bf16(af[i], bfr[j], acc[i][j], 0, 0, 0);
  }

  const int sec = bn >> 10;  // 0=q 1=k 2=v (block-uniform)
  if (sec == 2) {
    // ---- V: fp32 copy direct + V^T bf16 via LDS-staged per-wave transpose ----
    __syncthreads();  // all waves done reading As/Bs
    char* stg = reinterpret_cast<char*>((w < 2) ? (&As[0][0] + w * 4096)
                                                : (&Bs[0][0] + (w - 2) * 4096));
#pragma unroll
    for (int j = 0; j < 4; ++j) {
      const int gn = bn + wn * 64 + j * 16 + c;
      const float bv = bias[gn];
      const int cc = gn & 1023;
      const int ln = j * 16 + c;                 // local dd 0..63
#pragma unroll
      for (int i = 0; i < 4; ++i) {
        const int gm0 = bm + wm * 64 + i * 16 + q * 4;
        const int lm0 = i * 16 + q * 4;          // local tok 0..63 (4-run)
        float vals[4];
#pragma unroll
        for (int r = 0; r < 4; ++r) {
          vals[r] = acc[i][j][r] + bv;
          outbase[(size_t)8388608 + (size_t)(gm0 + r) * DMODEL + cc] = vals[r];
        }
        ushort4 tv;
        tv.x = f2bf(vals[0]); tv.y = f2bf(vals[1]);
        tv.z = f2bf(vals[2]); tv.w = f2bf(vals[3]);
        // staged layout: row ln (128B), byte offset (lm*2) XOR ((ln&7)<<4)
        *reinterpret_cast<ushort4*>(stg + ln * 128 + ((lm0 * 2) ^ ((ln & 7) << 4))) = tv;
      }
    }
    // readback (16B chunks, XOR-consistent) + coalesced V^T store
    const int gmb = bm + wm * 64;
    const int bb = gmb >> 11, tokb = gmb & 2047;
    const int hh = ((bn + wn * 64) >> 6) & 15;
    unsigned short* vrow = vtbf + ((size_t)(bb * NHEAD + hh) * DHEAD) * SEQ + tokb;
#pragma unroll
    for (int it = 0; it < 8; ++it) {
      const int r_ = (lane >> 3) + it * 8;       // dd row 0..63
      const int g = lane & 7;                    // 16B chunk along tok
      const uint4 val = *reinterpret_cast<const uint4*>(
          stg + r_ * 128 + (((unsigned)g << 4) ^ ((r_ & 7) << 4)));
      *reinterpret_cast<uint4*>(vrow + (size_t)r_ * SEQ + g * 8) = val;
    }
  } else {
#pragma unroll
    for (int j = 0; j < 4; ++j) {
      const int gn = bn + wn * 64 + j * 16 + c;
      const float bv = bias[gn];
      const int cc = gn & 1023, hh = cc >> 6, dd = cc & 63;
#pragma unroll
      for (int i = 0; i < 4; ++i) {
#pragma unroll
        for (int r = 0; r < 4; ++r) {
          const int gm = bm + wm * 64 + i * 16 + q * 4 + r;
          const int bb = gm >> 11, tok = gm & 2047;
          const float val = acc[i][j][r] + bv;
          const size_t hoff = ((size_t)(bb * NHEAD + hh) * SEQ + tok) * DHEAD + dd;
          if (sec == 0) {
            qbf[hoff] = f2bf(val * QSCALE);   // softmax scale folded into Q
          } else {
            outbase[(size_t)4194304 + (size_t)gm * DMODEL + cc] = val;
            kbf[hoff] = f2bf(val);
          }
        }
      }
    }
  }
}

// ---------------- flash attention (causal), S^T trick, 64-row Q tiles ----------------
// R4 structure (grid 1024, single-buffer, 2 barriers/tile) with T14 async-STAGE:
// K/V tile kt+1 is global_load'ed into REGISTERS right after QK^T (latency hides
// under softmax+PV), and ds_written to LDS at the top of the next iteration. The
// barrier after the ds_writes waits on lgkmcnt (~tens of cycles) instead of the old
// gl_lds16 vmcnt(0) drain (~400 cycles of exposed L2 latency per tile).
__global__ __launch_bounds__(256) void k_attn(
    const unsigned short* __restrict__ qbf, const unsigned short* __restrict__ kbf,
    const unsigned short* __restrict__ vtbf, unsigned short* __restrict__ aout) {
  __shared__ __attribute__((aligned(16))) unsigned short Ks[128 * 64];
  __shared__ __attribute__((aligned(16))) unsigned short Vs[64 * 128];

  const int tid = threadIdx.x, lane = tid & 63, w = tid >> 6;
  const int c = lane & 15, q = lane >> 4;
  const int oo = blockIdx.x >> 5, kk = oo & 7, ssl = oo >> 3;
  const int qsub = (ssl == 0) ? (31 - kk) : (ssl == 1) ? kk
                 : (ssl == 2) ? (23 - kk) : (8 + kk);
  const int bh = blockIdx.x & 31;
  const int kmax = qsub >> 1;
  const size_t hoff = (size_t)bh * SEQ * DHEAD;

  const unsigned short* qg = qbf + hoff + (size_t)(qsub * 64 + w * 16 + c) * DHEAD;
  const bf16x8 qb0 = *reinterpret_cast<const bf16x8*>(qg + q * 8);
  const bf16x8 qb1 = *reinterpret_cast<const bf16x8*>(qg + 32 + q * 8);

  f32x4 o[4] = {};
  float lpart = 0.f;  // per-lane partial denominator (reduced once at the end)
  const int qloc = (qsub & 1) * 64 + w * 16 + c;
  const int cx = c & 7;

  const int krow = tid >> 3, kswz = (tid & 7) ^ (krow & 7);
  const int vrow = tid >> 4, vswz = (tid & 15) ^ (vrow & 7);
  const unsigned short* kgb = kbf + hoff;
  const unsigned short* vgb = vtbf + (size_t)bh * DHEAD * SEQ;

  // prologue: load tile 0 into registers (same swizzled addresses the old
  // gl_lds16 path used as sources; LDS layout is unchanged).
  uint4 krg[4], vrg[4];
#pragma unroll
  for (int is = 0; is < 4; ++is)
    krg[is] = *reinterpret_cast<const uint4*>(kgb + (krow + is * 32) * 64 + kswz * 8);
#pragma unroll
  for (int is = 0; is < 4; ++is)
    vrg[is] = *reinterpret_cast<const uint4*>(vgb + (size_t)(vrow + is * 16) * SEQ + vswz * 8);

  for (int kt = 0; kt <= kmax; ++kt) {
    __syncthreads();  // A: all waves done reading Ks/Vs of tile kt-1
    // regs -> LDS (identical destination layout to the old gl_lds16 staging)
#pragma unroll
    for (int is = 0; is < 4; ++is)
      *reinterpret_cast<uint4*>(Ks + is * 2048 + tid * 8) = krg[is];
#pragma unroll
    for (int is = 0; is < 4; ++is)
      *reinterpret_cast<uint4*>(Vs + is * 2048 + tid * 8) = vrg[is];
    __syncthreads();  // B: waits on ds_writes (lgkmcnt) only — cheap

    f32x4 s[8];
    __builtin_amdgcn_s_setprio(1);
#pragma unroll
    for (int mi = 0; mi < 8; ++mi) {
      const unsigned short* kr = Ks + (mi * 16 + c) * 64;
      const bf16x8 ak0 = *reinterpret_cast<const bf16x8*>(kr + (q ^ cx) * 8);
      const bf16x8 ak1 = *reinterpret_cast<const bf16x8*>(kr + ((4 + q) ^ cx) * 8);
      f32x4 t = {};
      t = __builtin_amdgcn_mfma_f32_16x16x32_bf16(ak0, qb0, t, 0, 0, 0);
      t = __builtin_amdgcn_mfma_f32_16x16x32_bf16(ak1, qb1, t, 0, 0, 0);
      s[mi] = t;
    }
    __builtin_amdgcn_s_setprio(0);

    // issue next-tile loads NOW; latency hides under softmax + PV (~400 cyc)
    if (kt < kmax) {
      const unsigned short* kg = kgb + (size_t)(kt + 1) * 128 * DHEAD;
#pragma unroll
      for (int is = 0; is < 4; ++is)
        krg[is] = *reinterpret_cast<const uint4*>(kg + (krow + is * 32) * 64 + kswz * 8);
      const unsigned short* vg = vgb + (kt + 1) * 128;
#pragma unroll
      for (int is = 0; is < 4; ++is)
        vrg[is] = *reinterpret_cast<const uint4*>(vg + (size_t)(vrow + is * 16) * SEQ + vswz * 8);
    }

    if (kt == kmax) {
#pragma unroll
      for (int mi = 0; mi < 8; ++mi)
#pragma unroll
        for (int r = 0; r < 4; ++r)
          if (mi * 16 + q * 4 + r > qloc) s[mi][r] = -__builtin_inff();
    }

    s16x4 pb[8];
#pragma unroll
    for (int mi = 0; mi < 8; ++mi) {
      const float p0 = __builtin_amdgcn_exp2f(s[mi][0]);
      const float p1 = __builtin_amdgcn_exp2f(s[mi][1]);
      const float p2 = __builtin_amdgcn_exp2f(s[mi][2]);
      const float p3 = __builtin_amdgcn_exp2f(s[mi][3]);
      lpart += (p0 + p1) + (p2 + p3);
      union { s16x4 v; unsigned u[2]; } pk;
      pk.u[0] = __builtin_amdgcn_perm(__float_as_uint(p1), __float_as_uint(p0), 0x07060302u);
      pk.u[1] = __builtin_amdgcn_perm(__float_as_uint(p3), __float_as_uint(p2), 0x07060302u);
      pb[mi] = pk.v;
    }

    __builtin_amdgcn_s_setprio(1);
#pragma unroll
    for (int dm = 0; dm < 4; ++dm) {
      const unsigned short* vr = Vs + (dm * 16 + c) * 128 + (q & 1) * 4;
#pragma unroll
      for (int kf = 0; kf < 8; ++kf) {
        const s16x4 av = *reinterpret_cast<const s16x4*>(
            vr + (((kf * 2 + (q >> 1)) ^ cx) * 8));
        o[dm] = MFMA_PV(av, pb[kf], o[dm]);
      }
    }
    __builtin_amdgcn_s_setprio(0);
  }

  // final denominator reduce (q-groups hold disjoint k-slices of the same q-row)
  float lrun = lpart;
  lrun += __shfl_xor(lrun, 16);
  lrun += __shfl_xor(lrun, 32);

  __syncthreads();  // all waves done reading Ks -> safe to reuse as staging

  // ---- coalesced epilogue (R2-proven) ----
  const float linv = 1.0f / lrun;
  unsigned short* Ws = Ks + w * 1024;  // 2KB per wave, disjoint regions
#pragma unroll
  for (int dm = 0; dm < 4; ++dm) {
    ushort4 ov;
    ov.x = f2bf(o[dm][0] * linv);
    ov.y = f2bf(o[dm][1] * linv);
    ov.z = f2bf(o[dm][2] * linv);
    ov.w = f2bf(o[dm][3] * linv);
    const int bofs = c * 128 + ((dm * 32 + q * 8) ^ ((c & 7) << 4));  // bytes
    *reinterpret_cast<ushort4*>(Ws + (bofs >> 1)) = ov;
  }
  const int b = bh >> 4, h = bh & 15;
#pragma unroll
  for (int it = 0; it < 2; ++it) {
    const int r_ = (lane >> 3) + it * 8;
    const int g = lane & 7;
    const uint4 val = *reinterpret_cast<const uint4*>(
        Ws + ((r_ * 128 + (((unsigned)g ^ (r_ & 7)) << 4)) >> 1));
    const int row = b * SEQ + qsub * 64 + w * 16 + r_;
    *reinterpret_cast<uint4*>(aout + (size_t)row * DMODEL + h * 64 + g * 8) = val;
  }
}

// ---------------- GEMM2: 128x64 tiles, double-buffered, BK=32 (R4-proven) ----------
__global__ __launch_bounds__(256) void k_gemm_out(
    const unsigned short* __restrict__ A, const unsigned short* __restrict__ Bt,
    const float* __restrict__ bias, float* __restrict__ C) {
  __shared__ __attribute__((aligned(16))) unsigned short As[2][128 * 32];
  __shared__ __attribute__((aligned(16))) unsigned short Bs[2][64 * 32];
  const int tid = threadIdx.x, lane = tid & 63;
  const int w = tid >> 6, wm = w >> 1, wn = w & 1;
  const int c = lane & 15, q = lane >> 4;
  const int kc = (c & 3) ^ ((c >> 2) & 3);
  const int bm = blockIdx.x * 128, bn = blockIdx.y * 64;
  const int srow = tid >> 2;
  const int skey = (srow & 3) ^ ((srow >> 2) & 3);
  const int scolsw = (((tid & 3) ^ skey) << 3);
  const unsigned short* Ag = A + (size_t)(bm + srow) * DMODEL + scolsw;
  const unsigned short* Bg = Bt + (size_t)(bn + srow) * DMODEL + scolsw;
  f32x4 acc[4][2] = {};

  gl_lds16(Ag, As[0] + tid * 8);
  gl_lds16(Ag + (size_t)64 * DMODEL, As[0] + 2048 + tid * 8);
  gl_lds16(Bg, Bs[0] + tid * 8);

  for (int kt = 0; kt < 32; ++kt) {
    const int cur = kt & 1;
    __syncthreads();
    if (kt < 31) {
      const int k0 = (kt + 1) * 32;
      gl_lds16(Ag + k0, As[cur ^ 1] + tid * 8);
      gl_lds16(Ag + k0 + (size_t)64 * DMODEL, As[cur ^ 1] + 2048 + tid * 8);
      gl_lds16(Bg + k0, Bs[cur ^ 1] + tid * 8);
    }
    const int ch = (q ^ kc) << 3;
    bf16x8 af[4], bfr[2];
#pragma unroll
    for (int i = 0; i < 4; ++i)
      af[i] = *reinterpret_cast<const bf16x8*>(As[cur] + (wm * 64 + i * 16 + c) * 32 + ch);
#pragma unroll
    for (int j = 0; j < 2; ++j)
      bfr[j] = *reinterpret_cast<const bf16x8*>(Bs[cur] + (wn * 32 + j * 16 + c) * 32 + ch);
#pragma unroll
    for (int i = 0; i < 4; ++i)
#pragma unroll
      for (int j = 0; j < 2; ++j)
        acc[i][j] = __builtin_amdgcn_mfma_f32_16x16x32_bf16(af[i], bfr[j], acc[i][j], 0, 0, 0);
  }

#pragma unroll
  for (int j = 0; j < 2; ++j) {
    const int gn = bn + wn * 32 + j * 16 + c;
    const float bv = bias[gn];
#pragma unroll
    for (int i = 0; i < 4; ++i)
#pragma unroll
      for (int r = 0; r < 4; ++r) {
        const int gm = bm + wm * 64 + i * 16 + q * 4 + r;
        C[(size_t)gm * DMODEL + gn] = acc[i][j][r] + bv;
      }
  }
}

extern "C" void kernel_launch(void* const* d_in, const int* in_sizes, int n_in,
                              void* d_out, int out_size, void* d_ws, size_t ws_size,
                              hipStream_t stream) {
  (void)in_sizes; (void)n_in; (void)out_size; (void)ws_size;
  const float* input = (const float*)d_in[0];
  // d_in[1] = causal mask, implemented analytically
  const float* W_qkv = (const float*)d_in[2];
  const float* b_qkv = (const float*)d_in[3];
  const float* W_out = (const float*)d_in[4];
  const float* b_out = (const float*)d_in[5];
  float* out = (float*)d_out;

  unsigned char* ws = (unsigned char*)d_ws;
  unsigned short* Abf   = (unsigned short*)(ws + 0);          // 8 MB; dead after GEMM1
  unsigned short* WqkvT = (unsigned short*)(ws + 8388608);    // 6 MB
  unsigned short* WoutT = (unsigned short*)(ws + 14680064);   // 2 MB
  unsigned short* Qbf   = (unsigned short*)(ws + 16777216);   // 8 MB [B,H,L,64] (pre-scaled)
  unsigned short* Kbf   = (unsigned short*)(ws + 25165824);   // 8 MB [B,H,L,64]
  unsigned short* VTbf  = (unsigned short*)(ws + 33554432);   // 8 MB [B,H,64,L] (direct from GEMM1)
  unsigned short* Aout  = (unsigned short*)(ws + 41943040);   // 8 MB [4096][1024]

  k_prepass<<<8192, 256, 0, stream>>>(input, Abf, W_qkv, WqkvT, W_out, WoutT);
  k_gemm_qkv<<<dim3(32, 24), 256, 0, stream>>>(Abf, WqkvT, b_qkv, out, Qbf, Kbf, VTbf);
  k_attn<<<1024, 256, 0, stream>>>(Qbf, Kbf, VTbf, Aout);
  k_gemm_out<<<dim3(32, 16), 256, 0, stream>>>(Aout, WoutT, b_out, out);
}

// Round 9
// 188.647 us; speedup vs baseline: 1.3190x; 1.3190x over previous
//
#include <hip/hip_runtime.h>
#include <cstdint>

#define NHEAD 16
#define DHEAD 64
#define SEQ   2048
#define DMODEL 1024
#define MTOT  4096
#define NQKV  3072

typedef __bf16 bf16x8 __attribute__((ext_vector_type(8)));
typedef short  s16x4  __attribute__((ext_vector_type(4)));
typedef float  f32x4  __attribute__((ext_vector_type(4)));

__device__ __forceinline__ unsigned short f2bf(float f) {
  union { float f; unsigned u; } v; v.f = f;
  unsigned r = v.u + 0x7fffu + ((v.u >> 16) & 1u);
  return (unsigned short)(r >> 16);
}

// async global->LDS, 16B per lane. LDS dest must be wave-uniform base + lane*16.
__device__ __forceinline__ void gl_lds16(const void* g, void* l) {
  __builtin_amdgcn_global_load_lds(
      reinterpret_cast<const __attribute__((address_space(1))) unsigned int*>(
          reinterpret_cast<uintptr_t>(g)),
      reinterpret_cast<__attribute__((address_space(3))) unsigned int*>(
          reinterpret_cast<uintptr_t>(l)),
      16, 0, 0);
}

#if __has_builtin(__builtin_amdgcn_mfma_f32_16x16x16bf16_1k)
#define MFMA_PV(a, b, c) __builtin_amdgcn_mfma_f32_16x16x16bf16_1k(a, b, c, 0, 0, 0)
#else
__device__ __forceinline__ f32x4 mfma_pv_asm(s16x4 a, s16x4 b, f32x4 c) {
  f32x4 d;
  asm volatile("v_mfma_f32_16x16x16_bf16 %0, %1, %2, %3"
               : "=v"(d) : "v"(a), "v"(b), "v"(c));
  return d;
}
#define MFMA_PV(a, b, c) mfma_pv_asm(a, b, c)
#endif

// Q pre-scale: softmax scale folded into Q at GEMM1 (0.125 * log2(e)).
#define QSCALE 0.18033688011112042f

// ---------------- merged pre-pass: fp32->bf16 input cvt + both weight transposes ----
__global__ void k_prepass(const float* __restrict__ x, unsigned short* __restrict__ y,
                          const float* __restrict__ W0, unsigned short* __restrict__ T0,
                          const float* __restrict__ W1, unsigned short* __restrict__ T1) {
  __shared__ unsigned short t[32][33];
  const int bid = blockIdx.x;
  if (bid < 4096) {
    const int i = bid * 256 + threadIdx.x;
    float4 v = reinterpret_cast<const float4*>(x)[i];
    ushort4 o;
    o.x = f2bf(v.x); o.y = f2bf(v.y); o.z = f2bf(v.z); o.w = f2bf(v.w);
    reinterpret_cast<ushort4*>(y)[i] = o;
  } else {
    const int b2 = bid - 4096;
    const int bx = b2 & 127;           // 0..127 (96 for W_qkv, 32 for W_out)
    const int by = b2 >> 7;            // 0..31  (K/32 tiles)
    const float* W = (bx < 96) ? W0 : W1;
    unsigned short* WT = (bx < 96) ? T0 : T1;
    const int N = (bx < 96) ? 3072 : 1024;
    const int n0 = ((bx < 96) ? bx : (bx - 96)) * 32;
    const int k0 = by * 32;
    const int tx = threadIdx.x & 31, ty = threadIdx.x >> 5;
    for (int i = ty; i < 32; i += 8)
      t[i][tx] = f2bf(W[(size_t)(k0 + i) * N + n0 + tx]);
    __syncthreads();
    for (int i = ty; i < 32; i += 8)
      WT[(size_t)(n0 + i) * 1024 + k0 + tx] = t[tx][i];
  }
}

// ---------------- GEMM1: double-buffered LDS, 1 barrier/iter, BK=32 ----------------
// R0-proven main loop; R3-proven fused V^T epilogue; QSCALE kept; no XCD swizzle.
__global__ __launch_bounds__(256, 3) void k_gemm_qkv(
    const unsigned short* __restrict__ A, const unsigned short* __restrict__ Bt,
    const float* __restrict__ bias, float* __restrict__ outbase,
    unsigned short* __restrict__ qbf, unsigned short* __restrict__ kbf,
    unsigned short* __restrict__ vtbf) {
  __shared__ __attribute__((aligned(16))) unsigned short As[2][128 * 32];
  __shared__ __attribute__((aligned(16))) unsigned short Bs[2][128 * 32];
  const int tid = threadIdx.x, lane = tid & 63;
  const int w = tid >> 6, wm = w >> 1, wn = w & 1;
  const int c = lane & 15, q = lane >> 4;
  const int kc = (c & 3) ^ ((c >> 2) & 3);        // frag-read swizzle key
  const int bm = blockIdx.x * 128, bn = blockIdx.y * 128;
  const int srow = tid >> 2;
  const int skey = (srow & 3) ^ ((srow >> 2) & 3);
  const int scolsw = (((tid & 3) ^ skey) << 3);   // swizzled global source column
  const unsigned short* Ag = A + (size_t)(bm + srow) * DMODEL + scolsw;
  const unsigned short* Bg = Bt + (size_t)(bn + srow) * DMODEL + scolsw;
  f32x4 acc[4][4] = {};

  // stage tile 0 into buf 0
  gl_lds16(Ag, As[0] + tid * 8);
  gl_lds16(Ag + (size_t)64 * DMODEL, As[0] + 2048 + tid * 8);
  gl_lds16(Bg, Bs[0] + tid * 8);
  gl_lds16(Bg + (size_t)64 * DMODEL, Bs[0] + 2048 + tid * 8);

  for (int kt = 0; kt < 32; ++kt) {
    const int cur = kt & 1;
    __syncthreads();  // drains loads issued LAST iter (fully latency-hidden)
    if (kt < 31) {    // prefetch tile kt+1 into the other buffer
      const int k0 = (kt + 1) * 32;
      gl_lds16(Ag + k0, As[cur ^ 1] + tid * 8);
      gl_lds16(Ag + k0 + (size_t)64 * DMODEL, As[cur ^ 1] + 2048 + tid * 8);
      gl_lds16(Bg + k0, Bs[cur ^ 1] + tid * 8);
      gl_lds16(Bg + k0 + (size_t)64 * DMODEL, Bs[cur ^ 1] + 2048 + tid * 8);
    }
    const int ch = (q ^ kc) << 3;
    bf16x8 af[4], bfr[4];
#pragma unroll
    for (int i = 0; i < 4; ++i)
      af[i] = *reinterpret_cast<const bf16x8*>(As[cur] + (wm * 64 + i * 16 + c) * 32 + ch);
#pragma unroll
    for (int j = 0; j < 4; ++j)
      bfr[j] = *reinterpret_cast<const bf16x8*>(Bs[cur] + (wn * 64 + j * 16 + c) * 32 + ch);
#pragma unroll
    for (int i = 0; i < 4; ++i)
#pragma unroll
      for (int j = 0; j < 4; ++j)
        acc[i][j] = __builtin_amdgcn_mfma_f32_16x16x32_bf16(af[i], bfr[j], acc[i][j], 0, 0, 0);
  }

  const int sec = bn >> 10;  // 0=q 1=k 2=v (block-uniform)
  if (sec == 2) {
    // ---- V: fp32 copy direct + V^T bf16 via LDS-staged per-wave transpose ----
    __syncthreads();  // all waves done reading As/Bs
    char* stg = reinterpret_cast<char*>((w < 2) ? (&As[0][0] + w * 4096)
                                                : (&Bs[0][0] + (w - 2) * 4096));
#pragma unroll
    for (int j = 0; j < 4; ++j) {
      const int gn = bn + wn * 64 + j * 16 + c;
      const float bv = bias[gn];
      const int cc = gn & 1023;
      const int ln = j * 16 + c;                 // local dd 0..63
#pragma unroll
      for (int i = 0; i < 4; ++i) {
        const int gm0 = bm + wm * 64 + i * 16 + q * 4;
        const int lm0 = i * 16 + q * 4;          // local tok 0..63 (4-run)
        float vals[4];
#pragma unroll
        for (int r = 0; r < 4; ++r) {
          vals[r] = acc[i][j][r] + bv;
          outbase[(size_t)8388608 + (size_t)(gm0 + r) * DMODEL + cc] = vals[r];
        }
        ushort4 tv;
        tv.x = f2bf(vals[0]); tv.y = f2bf(vals[1]);
        tv.z = f2bf(vals[2]); tv.w = f2bf(vals[3]);
        // staged layout: row ln (128B), byte offset (lm*2) XOR ((ln&7)<<4)
        *reinterpret_cast<ushort4*>(stg + ln * 128 + ((lm0 * 2) ^ ((ln & 7) << 4))) = tv;
      }
    }
    // readback (16B chunks, XOR-consistent) + coalesced V^T store
    const int gmb = bm + wm * 64;
    const int bb = gmb >> 11, tokb = gmb & 2047;
    const int hh = ((bn + wn * 64) >> 6) & 15;
    unsigned short* vrow = vtbf + ((size_t)(bb * NHEAD + hh) * DHEAD) * SEQ + tokb;
#pragma unroll
    for (int it = 0; it < 8; ++it) {
      const int r_ = (lane >> 3) + it * 8;       // dd row 0..63
      const int g = lane & 7;                    // 16B chunk along tok
      const uint4 val = *reinterpret_cast<const uint4*>(
          stg + r_ * 128 + (((unsigned)g << 4) ^ ((r_ & 7) << 4)));
      *reinterpret_cast<uint4*>(vrow + (size_t)r_ * SEQ + g * 8) = val;
    }
  } else {
#pragma unroll
    for (int j = 0; j < 4; ++j) {
      const int gn = bn + wn * 64 + j * 16 + c;
      const float bv = bias[gn];
      const int cc = gn & 1023, hh = cc >> 6, dd = cc & 63;
#pragma unroll
      for (int i = 0; i < 4; ++i) {
#pragma unroll
        for (int r = 0; r < 4; ++r) {
          const int gm = bm + wm * 64 + i * 16 + q * 4 + r;
          const int bb = gm >> 11, tok = gm & 2047;
          const float val = acc[i][j][r] + bv;
          const size_t hoff = ((size_t)(bb * NHEAD + hh) * SEQ + tok) * DHEAD + dd;
          if (sec == 0) {
            qbf[hoff] = f2bf(val * QSCALE);   // softmax scale folded into Q
          } else {
            outbase[(size_t)4194304 + (size_t)gm * DMODEL + cc] = val;
            kbf[hoff] = f2bf(val);
          }
        }
      }
    }
  }
}

// ---------------- flash attention (causal), S^T trick, 64-row Q tiles ----------------
// R4/R5-proven structure restored: gl_lds16 single-buffer 2-barrier staging (async
// DMA path, no VGPR staging — R8's reg-staging spilled to scratch, 231MB writes),
// no-max sum-exp softmax, pre-scaled Q, setprio, coalesced LDS-staged epilogue.
__global__ __launch_bounds__(256) void k_attn(
    const unsigned short* __restrict__ qbf, const unsigned short* __restrict__ kbf,
    const unsigned short* __restrict__ vtbf, unsigned short* __restrict__ aout) {
  __shared__ __attribute__((aligned(16))) unsigned short Ks[128 * 64];
  __shared__ __attribute__((aligned(16))) unsigned short Vs[64 * 128];

  const int tid = threadIdx.x, lane = tid & 63, w = tid >> 6;
  const int c = lane & 15, q = lane >> 4;
  const int oo = blockIdx.x >> 5, kk = oo & 7, ssl = oo >> 3;
  const int qsub = (ssl == 0) ? (31 - kk) : (ssl == 1) ? kk
                 : (ssl == 2) ? (23 - kk) : (8 + kk);
  const int bh = blockIdx.x & 31;
  const int kmax = qsub >> 1;
  const size_t hoff = (size_t)bh * SEQ * DHEAD;

  const unsigned short* qg = qbf + hoff + (size_t)(qsub * 64 + w * 16 + c) * DHEAD;
  const bf16x8 qb0 = *reinterpret_cast<const bf16x8*>(qg + q * 8);
  const bf16x8 qb1 = *reinterpret_cast<const bf16x8*>(qg + 32 + q * 8);

  f32x4 o[4] = {};
  float lpart = 0.f;  // per-lane partial denominator (reduced once at the end)
  const int qloc = (qsub & 1) * 64 + w * 16 + c;
  const int cx = c & 7;

  const int krow = tid >> 3, kswz = (tid & 7) ^ (krow & 7);
  const int vrow = tid >> 4, vswz = (tid & 15) ^ (vrow & 7);
  const unsigned short* kgb = kbf + hoff;
  const unsigned short* vgb = vtbf + (size_t)bh * DHEAD * SEQ;

  for (int kt = 0; kt <= kmax; ++kt) {
    __syncthreads();
    const unsigned short* kg = kgb + (size_t)kt * 128 * DHEAD;
#pragma unroll
    for (int is = 0; is < 4; ++is)
      gl_lds16(kg + (krow + is * 32) * 64 + kswz * 8, Ks + is * 2048 + tid * 8);
    const unsigned short* vg = vgb + kt * 128;
#pragma unroll
    for (int is = 0; is < 4; ++is)
      gl_lds16(vg + (size_t)(vrow + is * 16) * SEQ + vswz * 8, Vs + is * 2048 + tid * 8);
    __syncthreads();

    f32x4 s[8];
    __builtin_amdgcn_s_setprio(1);
#pragma unroll
    for (int mi = 0; mi < 8; ++mi) {
      const unsigned short* kr = Ks + (mi * 16 + c) * 64;
      const bf16x8 ak0 = *reinterpret_cast<const bf16x8*>(kr + (q ^ cx) * 8);
      const bf16x8 ak1 = *reinterpret_cast<const bf16x8*>(kr + ((4 + q) ^ cx) * 8);
      f32x4 t = {};
      t = __builtin_amdgcn_mfma_f32_16x16x32_bf16(ak0, qb0, t, 0, 0, 0);
      t = __builtin_amdgcn_mfma_f32_16x16x32_bf16(ak1, qb1, t, 0, 0, 0);
      s[mi] = t;
    }
    __builtin_amdgcn_s_setprio(0);

    if (kt == kmax) {
#pragma unroll
      for (int mi = 0; mi < 8; ++mi)
#pragma unroll
        for (int r = 0; r < 4; ++r)
          if (mi * 16 + q * 4 + r > qloc) s[mi][r] = -__builtin_inff();
    }

    s16x4 pb[8];
#pragma unroll
    for (int mi = 0; mi < 8; ++mi) {
      const float p0 = __builtin_amdgcn_exp2f(s[mi][0]);
      const float p1 = __builtin_amdgcn_exp2f(s[mi][1]);
      const float p2 = __builtin_amdgcn_exp2f(s[mi][2]);
      const float p3 = __builtin_amdgcn_exp2f(s[mi][3]);
      lpart += (p0 + p1) + (p2 + p3);
      union { s16x4 v; unsigned u[2]; } pk;
      pk.u[0] = __builtin_amdgcn_perm(__float_as_uint(p1), __float_as_uint(p0), 0x07060302u);
      pk.u[1] = __builtin_amdgcn_perm(__float_as_uint(p3), __float_as_uint(p2), 0x07060302u);
      pb[mi] = pk.v;
    }

    __builtin_amdgcn_s_setprio(1);
#pragma unroll
    for (int dm = 0; dm < 4; ++dm) {
      const unsigned short* vr = Vs + (dm * 16 + c) * 128 + (q & 1) * 4;
#pragma unroll
      for (int kf = 0; kf < 8; ++kf) {
        const s16x4 av = *reinterpret_cast<const s16x4*>(
            vr + (((kf * 2 + (q >> 1)) ^ cx) * 8));
        o[dm] = MFMA_PV(av, pb[kf], o[dm]);
      }
    }
    __builtin_amdgcn_s_setprio(0);
  }

  // final denominator reduce (q-groups hold disjoint k-slices of the same q-row)
  float lrun = lpart;
  lrun += __shfl_xor(lrun, 16);
  lrun += __shfl_xor(lrun, 32);

  __syncthreads();  // all waves done reading Ks -> safe to reuse as staging

  // ---- coalesced epilogue (R2-proven) ----
  const float linv = 1.0f / lrun;
  unsigned short* Ws = Ks + w * 1024;  // 2KB per wave, disjoint regions
#pragma unroll
  for (int dm = 0; dm < 4; ++dm) {
    ushort4 ov;
    ov.x = f2bf(o[dm][0] * linv);
    ov.y = f2bf(o[dm][1] * linv);
    ov.z = f2bf(o[dm][2] * linv);
    ov.w = f2bf(o[dm][3] * linv);
    const int bofs = c * 128 + ((dm * 32 + q * 8) ^ ((c & 7) << 4));  // bytes
    *reinterpret_cast<ushort4*>(Ws + (bofs >> 1)) = ov;
  }
  const int b = bh >> 4, h = bh & 15;
#pragma unroll
  for (int it = 0; it < 2; ++it) {
    const int r_ = (lane >> 3) + it * 8;
    const int g = lane & 7;
    const uint4 val = *reinterpret_cast<const uint4*>(
        Ws + ((r_ * 128 + (((unsigned)g ^ (r_ & 7)) << 4)) >> 1));
    const int row = b * SEQ + qsub * 64 + w * 16 + r_;
    *reinterpret_cast<uint4*>(aout + (size_t)row * DMODEL + h * 64 + g * 8) = val;
  }
}

// ---------------- GEMM2: 128x64 tiles, double-buffered, BK=32 (R4-proven) ----------
__global__ __launch_bounds__(256) void k_gemm_out(
    const unsigned short* __restrict__ A, const unsigned short* __restrict__ Bt,
    const float* __restrict__ bias, float* __restrict__ C) {
  __shared__ __attribute__((aligned(16))) unsigned short As[2][128 * 32];
  __shared__ __attribute__((aligned(16))) unsigned short Bs[2][64 * 32];
  const int tid = threadIdx.x, lane = tid & 63;
  const int w = tid >> 6, wm = w >> 1, wn = w & 1;
  const int c = lane & 15, q = lane >> 4;
  const int kc = (c & 3) ^ ((c >> 2) & 3);
  const int bm = blockIdx.x * 128, bn = blockIdx.y * 64;
  const int srow = tid >> 2;
  const int skey = (srow & 3) ^ ((srow >> 2) & 3);
  const int scolsw = (((tid & 3) ^ skey) << 3);
  const unsigned short* Ag = A + (size_t)(bm + srow) * DMODEL + scolsw;
  const unsigned short* Bg = Bt + (size_t)(bn + srow) * DMODEL + scolsw;
  f32x4 acc[4][2] = {};

  gl_lds16(Ag, As[0] + tid * 8);
  gl_lds16(Ag + (size_t)64 * DMODEL, As[0] + 2048 + tid * 8);
  gl_lds16(Bg, Bs[0] + tid * 8);

  for (int kt = 0; kt < 32; ++kt) {
    const int cur = kt & 1;
    __syncthreads();
    if (kt < 31) {
      const int k0 = (kt + 1) * 32;
      gl_lds16(Ag + k0, As[cur ^ 1] + tid * 8);
      gl_lds16(Ag + k0 + (size_t)64 * DMODEL, As[cur ^ 1] + 2048 + tid * 8);
      gl_lds16(Bg + k0, Bs[cur ^ 1] + tid * 8);
    }
    const int ch = (q ^ kc) << 3;
    bf16x8 af[4], bfr[2];
#pragma unroll
    for (int i = 0; i < 4; ++i)
      af[i] = *reinterpret_cast<const bf16x8*>(As[cur] + (wm * 64 + i * 16 + c) * 32 + ch);
#pragma unroll
    for (int j = 0; j < 2; ++j)
      bfr[j] = *reinterpret_cast<const bf16x8*>(Bs[cur] + (wn * 32 + j * 16 + c) * 32 + ch);
#pragma unroll
    for (int i = 0; i < 4; ++i)
#pragma unroll
      for (int j = 0; j < 2; ++j)
        acc[i][j] = __builtin_amdgcn_mfma_f32_16x16x32_bf16(af[i], bfr[j], acc[i][j], 0, 0, 0);
  }

#pragma unroll
  for (int j = 0; j < 2; ++j) {
    const int gn = bn + wn * 32 + j * 16 + c;
    const float bv = bias[gn];
#pragma unroll
    for (int i = 0; i < 4; ++i)
#pragma unroll
      for (int r = 0; r < 4; ++r) {
        const int gm = bm + wm * 64 + i * 16 + q * 4 + r;
        C[(size_t)gm * DMODEL + gn] = acc[i][j][r] + bv;
      }
  }
}

extern "C" void kernel_launch(void* const* d_in, const int* in_sizes, int n_in,
                              void* d_out, int out_size, void* d_ws, size_t ws_size,
                              hipStream_t stream) {
  (void)in_sizes; (void)n_in; (void)out_size; (void)ws_size;
  const float* input = (const float*)d_in[0];
  // d_in[1] = causal mask, implemented analytically
  const float* W_qkv = (const float*)d_in[2];
  const float* b_qkv = (const float*)d_in[3];
  const float* W_out = (const float*)d_in[4];
  const float* b_out = (const float*)d_in[5];
  float* out = (float*)d_out;

  unsigned char* ws = (unsigned char*)d_ws;
  unsigned short* Abf   = (unsigned short*)(ws + 0);          // 8 MB; dead after GEMM1
  unsigned short* WqkvT = (unsigned short*)(ws + 8388608);    // 6 MB
  unsigned short* WoutT = (unsigned short*)(ws + 14680064);   // 2 MB
  unsigned short* Qbf   = (unsigned short*)(ws + 16777216);   // 8 MB [B,H,L,64] (pre-scaled)
  unsigned short* Kbf   = (unsigned short*)(ws + 25165824);   // 8 MB [B,H,L,64]
  unsigned short* VTbf  = (unsigned short*)(ws + 33554432);   // 8 MB [B,H,64,L] (direct from GEMM1)
  unsigned short* Aout  = (unsigned short*)(ws + 41943040);   // 8 MB [4096][1024]

  k_prepass<<<8192, 256, 0, stream>>>(input, Abf, W_qkv, WqkvT, W_out, WoutT);
  k_gemm_qkv<<<dim3(32, 24), 256, 0, stream>>>(Abf, WqkvT, b_qkv, out, Qbf, Kbf, VTbf);
  k_attn<<<1024, 256, 0, stream>>>(Qbf, Kbf, VTbf, Aout);
  k_gemm_out<<<dim3(32, 16), 256, 0, stream>>>(Aout, WoutT, b_out, out);
}

// Round 10
// 187.770 us; speedup vs baseline: 1.3251x; 1.0047x over previous
//
#include <hip/hip_runtime.h>
#include <cstdint>

#define NHEAD 16
#define DHEAD 64
#define SEQ   2048
#define DMODEL 1024
#define MTOT  4096
#define NQKV  3072

typedef __bf16 bf16x8 __attribute__((ext_vector_type(8)));
typedef short  s16x4  __attribute__((ext_vector_type(4)));
typedef float  f32x4  __attribute__((ext_vector_type(4)));

__device__ __forceinline__ unsigned short f2bf(float f) {
  union { float f; unsigned u; } v; v.f = f;
  unsigned r = v.u + 0x7fffu + ((v.u >> 16) & 1u);
  return (unsigned short)(r >> 16);
}

// async global->LDS, 16B per lane. LDS dest must be wave-uniform base + lane*16.
__device__ __forceinline__ void gl_lds16(const void* g, void* l) {
  __builtin_amdgcn_global_load_lds(
      reinterpret_cast<const __attribute__((address_space(1))) unsigned int*>(
          reinterpret_cast<uintptr_t>(g)),
      reinterpret_cast<__attribute__((address_space(3))) unsigned int*>(
          reinterpret_cast<uintptr_t>(l)),
      16, 0, 0);
}

#if __has_builtin(__builtin_amdgcn_mfma_f32_16x16x16bf16_1k)
#define MFMA_PV(a, b, c) __builtin_amdgcn_mfma_f32_16x16x16bf16_1k(a, b, c, 0, 0, 0)
#else
__device__ __forceinline__ f32x4 mfma_pv_asm(s16x4 a, s16x4 b, f32x4 c) {
  f32x4 d;
  asm volatile("v_mfma_f32_16x16x16_bf16 %0, %1, %2, %3"
               : "=v"(d) : "v"(a), "v"(b), "v"(c));
  return d;
}
#define MFMA_PV(a, b, c) mfma_pv_asm(a, b, c)
#endif

// Q pre-scale: softmax scale folded into Q at GEMM1 (0.125 * log2(e)).
#define QSCALE 0.18033688011112042f

// ---------------- merged pre-pass: fp32->bf16 input cvt + both weight transposes ----
__global__ void k_prepass(const float* __restrict__ x, unsigned short* __restrict__ y,
                          const float* __restrict__ W0, unsigned short* __restrict__ T0,
                          const float* __restrict__ W1, unsigned short* __restrict__ T1) {
  __shared__ unsigned short t[32][33];
  const int bid = blockIdx.x;
  if (bid < 4096) {
    const int i = bid * 256 + threadIdx.x;
    float4 v = reinterpret_cast<const float4*>(x)[i];
    ushort4 o;
    o.x = f2bf(v.x); o.y = f2bf(v.y); o.z = f2bf(v.z); o.w = f2bf(v.w);
    reinterpret_cast<ushort4*>(y)[i] = o;
  } else {
    const int b2 = bid - 4096;
    const int bx = b2 & 127;           // 0..127 (96 for W_qkv, 32 for W_out)
    const int by = b2 >> 7;            // 0..31  (K/32 tiles)
    const float* W = (bx < 96) ? W0 : W1;
    unsigned short* WT = (bx < 96) ? T0 : T1;
    const int N = (bx < 96) ? 3072 : 1024;
    const int n0 = ((bx < 96) ? bx : (bx - 96)) * 32;
    const int k0 = by * 32;
    const int tx = threadIdx.x & 31, ty = threadIdx.x >> 5;
    for (int i = ty; i < 32; i += 8)
      t[i][tx] = f2bf(W[(size_t)(k0 + i) * N + n0 + tx]);
    __syncthreads();
    for (int i = ty; i < 32; i += 8)
      WT[(size_t)(n0 + i) * 1024 + k0 + tx] = t[tx][i];
  }
}

// ---------------- GEMM1: double-buffered LDS, 1 barrier/iter, BK=32 ----------------
// R0-proven main loop; R3-proven fused V^T epilogue; QSCALE kept; no XCD swizzle.
// (Quad-buffering NOT applied here: 64KB LDS would drop occupancy 3->2 blocks/CU,
// the known m132-class regression.)
__global__ __launch_bounds__(256, 3) void k_gemm_qkv(
    const unsigned short* __restrict__ A, const unsigned short* __restrict__ Bt,
    const float* __restrict__ bias, float* __restrict__ outbase,
    unsigned short* __restrict__ qbf, unsigned short* __restrict__ kbf,
    unsigned short* __restrict__ vtbf) {
  __shared__ __attribute__((aligned(16))) unsigned short As[2][128 * 32];
  __shared__ __attribute__((aligned(16))) unsigned short Bs[2][128 * 32];
  const int tid = threadIdx.x, lane = tid & 63;
  const int w = tid >> 6, wm = w >> 1, wn = w & 1;
  const int c = lane & 15, q = lane >> 4;
  const int kc = (c & 3) ^ ((c >> 2) & 3);        // frag-read swizzle key
  const int bm = blockIdx.x * 128, bn = blockIdx.y * 128;
  const int srow = tid >> 2;
  const int skey = (srow & 3) ^ ((srow >> 2) & 3);
  const int scolsw = (((tid & 3) ^ skey) << 3);   // swizzled global source column
  const unsigned short* Ag = A + (size_t)(bm + srow) * DMODEL + scolsw;
  const unsigned short* Bg = Bt + (size_t)(bn + srow) * DMODEL + scolsw;
  f32x4 acc[4][4] = {};

  // stage tile 0 into buf 0
  gl_lds16(Ag, As[0] + tid * 8);
  gl_lds16(Ag + (size_t)64 * DMODEL, As[0] + 2048 + tid * 8);
  gl_lds16(Bg, Bs[0] + tid * 8);
  gl_lds16(Bg + (size_t)64 * DMODEL, Bs[0] + 2048 + tid * 8);

  for (int kt = 0; kt < 32; ++kt) {
    const int cur = kt & 1;
    __syncthreads();  // drains loads issued LAST iter (fully latency-hidden)
    if (kt < 31) {    // prefetch tile kt+1 into the other buffer
      const int k0 = (kt + 1) * 32;
      gl_lds16(Ag + k0, As[cur ^ 1] + tid * 8);
      gl_lds16(Ag + k0 + (size_t)64 * DMODEL, As[cur ^ 1] + 2048 + tid * 8);
      gl_lds16(Bg + k0, Bs[cur ^ 1] + tid * 8);
      gl_lds16(Bg + k0 + (size_t)64 * DMODEL, Bs[cur ^ 1] + 2048 + tid * 8);
    }
    const int ch = (q ^ kc) << 3;
    bf16x8 af[4], bfr[4];
#pragma unroll
    for (int i = 0; i < 4; ++i)
      af[i] = *reinterpret_cast<const bf16x8*>(As[cur] + (wm * 64 + i * 16 + c) * 32 + ch);
#pragma unroll
    for (int j = 0; j < 4; ++j)
      bfr[j] = *reinterpret_cast<const bf16x8*>(Bs[cur] + (wn * 64 + j * 16 + c) * 32 + ch);
#pragma unroll
    for (int i = 0; i < 4; ++i)
#pragma unroll
      for (int j = 0; j < 4; ++j)
        acc[i][j] = __builtin_amdgcn_mfma_f32_16x16x32_bf16(af[i], bfr[j], acc[i][j], 0, 0, 0);
  }

  const int sec = bn >> 10;  // 0=q 1=k 2=v (block-uniform)
  if (sec == 2) {
    // ---- V: fp32 copy direct + V^T bf16 via LDS-staged per-wave transpose ----
    __syncthreads();  // all waves done reading As/Bs
    char* stg = reinterpret_cast<char*>((w < 2) ? (&As[0][0] + w * 4096)
                                                : (&Bs[0][0] + (w - 2) * 4096));
#pragma unroll
    for (int j = 0; j < 4; ++j) {
      const int gn = bn + wn * 64 + j * 16 + c;
      const float bv = bias[gn];
      const int cc = gn & 1023;
      const int ln = j * 16 + c;                 // local dd 0..63
#pragma unroll
      for (int i = 0; i < 4; ++i) {
        const int gm0 = bm + wm * 64 + i * 16 + q * 4;
        const int lm0 = i * 16 + q * 4;          // local tok 0..63 (4-run)
        float vals[4];
#pragma unroll
        for (int r = 0; r < 4; ++r) {
          vals[r] = acc[i][j][r] + bv;
          outbase[(size_t)8388608 + (size_t)(gm0 + r) * DMODEL + cc] = vals[r];
        }
        ushort4 tv;
        tv.x = f2bf(vals[0]); tv.y = f2bf(vals[1]);
        tv.z = f2bf(vals[2]); tv.w = f2bf(vals[3]);
        // staged layout: row ln (128B), byte offset (lm*2) XOR ((ln&7)<<4)
        *reinterpret_cast<ushort4*>(stg + ln * 128 + ((lm0 * 2) ^ ((ln & 7) << 4))) = tv;
      }
    }
    // readback (16B chunks, XOR-consistent) + coalesced V^T store
    const int gmb = bm + wm * 64;
    const int bb = gmb >> 11, tokb = gmb & 2047;
    const int hh = ((bn + wn * 64) >> 6) & 15;
    unsigned short* vrow = vtbf + ((size_t)(bb * NHEAD + hh) * DHEAD) * SEQ + tokb;
#pragma unroll
    for (int it = 0; it < 8; ++it) {
      const int r_ = (lane >> 3) + it * 8;       // dd row 0..63
      const int g = lane & 7;                    // 16B chunk along tok
      const uint4 val = *reinterpret_cast<const uint4*>(
          stg + r_ * 128 + (((unsigned)g << 4) ^ ((r_ & 7) << 4)));
      *reinterpret_cast<uint4*>(vrow + (size_t)r_ * SEQ + g * 8) = val;
    }
  } else {
#pragma unroll
    for (int j = 0; j < 4; ++j) {
      const int gn = bn + wn * 64 + j * 16 + c;
      const float bv = bias[gn];
      const int cc = gn & 1023, hh = cc >> 6, dd = cc & 63;
#pragma unroll
      for (int i = 0; i < 4; ++i) {
#pragma unroll
        for (int r = 0; r < 4; ++r) {
          const int gm = bm + wm * 64 + i * 16 + q * 4 + r;
          const int bb = gm >> 11, tok = gm & 2047;
          const float val = acc[i][j][r] + bv;
          const size_t hoff = ((size_t)(bb * NHEAD + hh) * SEQ + tok) * DHEAD + dd;
          if (sec == 0) {
            qbf[hoff] = f2bf(val * QSCALE);   // softmax scale folded into Q
          } else {
            outbase[(size_t)4194304 + (size_t)gm * DMODEL + cc] = val;
            kbf[hoff] = f2bf(val);
          }
        }
      }
    }
  }
}

// ---------------- flash attention (causal), S^T trick, 64-row Q tiles ----------------
// R9-proven (frozen): gl_lds16 single-buffer 2-barrier staging, no-max sum-exp
// softmax, pre-scaled Q, setprio, coalesced LDS-staged epilogue.
__global__ __launch_bounds__(256) void k_attn(
    const unsigned short* __restrict__ qbf, const unsigned short* __restrict__ kbf,
    const unsigned short* __restrict__ vtbf, unsigned short* __restrict__ aout) {
  __shared__ __attribute__((aligned(16))) unsigned short Ks[128 * 64];
  __shared__ __attribute__((aligned(16))) unsigned short Vs[64 * 128];

  const int tid = threadIdx.x, lane = tid & 63, w = tid >> 6;
  const int c = lane & 15, q = lane >> 4;
  const int oo = blockIdx.x >> 5, kk = oo & 7, ssl = oo >> 3;
  const int qsub = (ssl == 0) ? (31 - kk) : (ssl == 1) ? kk
                 : (ssl == 2) ? (23 - kk) : (8 + kk);
  const int bh = blockIdx.x & 31;
  const int kmax = qsub >> 1;
  const size_t hoff = (size_t)bh * SEQ * DHEAD;

  const unsigned short* qg = qbf + hoff + (size_t)(qsub * 64 + w * 16 + c) * DHEAD;
  const bf16x8 qb0 = *reinterpret_cast<const bf16x8*>(qg + q * 8);
  const bf16x8 qb1 = *reinterpret_cast<const bf16x8*>(qg + 32 + q * 8);

  f32x4 o[4] = {};
  float lpart = 0.f;  // per-lane partial denominator (reduced once at the end)
  const int qloc = (qsub & 1) * 64 + w * 16 + c;
  const int cx = c & 7;

  const int krow = tid >> 3, kswz = (tid & 7) ^ (krow & 7);
  const int vrow = tid >> 4, vswz = (tid & 15) ^ (vrow & 7);
  const unsigned short* kgb = kbf + hoff;
  const unsigned short* vgb = vtbf + (size_t)bh * DHEAD * SEQ;

  for (int kt = 0; kt <= kmax; ++kt) {
    __syncthreads();
    const unsigned short* kg = kgb + (size_t)kt * 128 * DHEAD;
#pragma unroll
    for (int is = 0; is < 4; ++is)
      gl_lds16(kg + (krow + is * 32) * 64 + kswz * 8, Ks + is * 2048 + tid * 8);
    const unsigned short* vg = vgb + kt * 128;
#pragma unroll
    for (int is = 0; is < 4; ++is)
      gl_lds16(vg + (size_t)(vrow + is * 16) * SEQ + vswz * 8, Vs + is * 2048 + tid * 8);
    __syncthreads();

    f32x4 s[8];
    __builtin_amdgcn_s_setprio(1);
#pragma unroll
    for (int mi = 0; mi < 8; ++mi) {
      const unsigned short* kr = Ks + (mi * 16 + c) * 64;
      const bf16x8 ak0 = *reinterpret_cast<const bf16x8*>(kr + (q ^ cx) * 8);
      const bf16x8 ak1 = *reinterpret_cast<const bf16x8*>(kr + ((4 + q) ^ cx) * 8);
      f32x4 t = {};
      t = __builtin_amdgcn_mfma_f32_16x16x32_bf16(ak0, qb0, t, 0, 0, 0);
      t = __builtin_amdgcn_mfma_f32_16x16x32_bf16(ak1, qb1, t, 0, 0, 0);
      s[mi] = t;
    }
    __builtin_amdgcn_s_setprio(0);

    if (kt == kmax) {
#pragma unroll
      for (int mi = 0; mi < 8; ++mi)
#pragma unroll
        for (int r = 0; r < 4; ++r)
          if (mi * 16 + q * 4 + r > qloc) s[mi][r] = -__builtin_inff();
    }

    s16x4 pb[8];
#pragma unroll
    for (int mi = 0; mi < 8; ++mi) {
      const float p0 = __builtin_amdgcn_exp2f(s[mi][0]);
      const float p1 = __builtin_amdgcn_exp2f(s[mi][1]);
      const float p2 = __builtin_amdgcn_exp2f(s[mi][2]);
      const float p3 = __builtin_amdgcn_exp2f(s[mi][3]);
      lpart += (p0 + p1) + (p2 + p3);
      union { s16x4 v; unsigned u[2]; } pk;
      pk.u[0] = __builtin_amdgcn_perm(__float_as_uint(p1), __float_as_uint(p0), 0x07060302u);
      pk.u[1] = __builtin_amdgcn_perm(__float_as_uint(p3), __float_as_uint(p2), 0x07060302u);
      pb[mi] = pk.v;
    }

    __builtin_amdgcn_s_setprio(1);
#pragma unroll
    for (int dm = 0; dm < 4; ++dm) {
      const unsigned short* vr = Vs + (dm * 16 + c) * 128 + (q & 1) * 4;
#pragma unroll
      for (int kf = 0; kf < 8; ++kf) {
        const s16x4 av = *reinterpret_cast<const s16x4*>(
            vr + (((kf * 2 + (q >> 1)) ^ cx) * 8));
        o[dm] = MFMA_PV(av, pb[kf], o[dm]);
      }
    }
    __builtin_amdgcn_s_setprio(0);
  }

  // final denominator reduce (q-groups hold disjoint k-slices of the same q-row)
  float lrun = lpart;
  lrun += __shfl_xor(lrun, 16);
  lrun += __shfl_xor(lrun, 32);

  __syncthreads();  // all waves done reading Ks -> safe to reuse as staging

  // ---- coalesced epilogue (R2-proven) ----
  const float linv = 1.0f / lrun;
  unsigned short* Ws = Ks + w * 1024;  // 2KB per wave, disjoint regions
#pragma unroll
  for (int dm = 0; dm < 4; ++dm) {
    ushort4 ov;
    ov.x = f2bf(o[dm][0] * linv);
    ov.y = f2bf(o[dm][1] * linv);
    ov.z = f2bf(o[dm][2] * linv);
    ov.w = f2bf(o[dm][3] * linv);
    const int bofs = c * 128 + ((dm * 32 + q * 8) ^ ((c & 7) << 4));  // bytes
    *reinterpret_cast<ushort4*>(Ws + (bofs >> 1)) = ov;
  }
  const int b = bh >> 4, h = bh & 15;
#pragma unroll
  for (int it = 0; it < 2; ++it) {
    const int r_ = (lane >> 3) + it * 8;
    const int g = lane & 7;
    const uint4 val = *reinterpret_cast<const uint4*>(
        Ws + ((r_ * 128 + (((unsigned)g ^ (r_ & 7)) << 4)) >> 1));
    const int row = b * SEQ + qsub * 64 + w * 16 + r_;
    *reinterpret_cast<uint4*>(aout + (size_t)row * DMODEL + h * 64 + g * 8) = val;
  }
}

// ---------------- GEMM2: 128x64 tiles, QUAD-buffered, BK=32 (R10) ----------------
// Same proven BK=32 addressing/swizzle; 4 LDS buffers so one barrier covers TWO
// K-tiles: prefetch kt+2,kt+3 / compute kt,kt+1 (already landed). Barriers 32->16,
// 16 MFMA/barrier. LDS 48KB -> 3 blocks/CU >= the grid's 2/CU (no residency cliff).
__global__ __launch_bounds__(256) void k_gemm_out(
    const unsigned short* __restrict__ A, const unsigned short* __restrict__ Bt,
    const float* __restrict__ bias, float* __restrict__ C) {
  __shared__ __attribute__((aligned(16))) unsigned short As[4][128 * 32];
  __shared__ __attribute__((aligned(16))) unsigned short Bs[4][64 * 32];
  const int tid = threadIdx.x, lane = tid & 63;
  const int w = tid >> 6, wm = w >> 1, wn = w & 1;
  const int c = lane & 15, q = lane >> 4;
  const int kc = (c & 3) ^ ((c >> 2) & 3);
  const int bm = blockIdx.x * 128, bn = blockIdx.y * 64;
  const int srow = tid >> 2;
  const int skey = (srow & 3) ^ ((srow >> 2) & 3);
  const int scolsw = (((tid & 3) ^ skey) << 3);
  const unsigned short* Ag = A + (size_t)(bm + srow) * DMODEL + scolsw;
  const unsigned short* Bg = Bt + (size_t)(bn + srow) * DMODEL + scolsw;
  f32x4 acc[4][2] = {};

  // stage tiles 0,1 into buffers 0,1
#pragma unroll
  for (int t = 0; t < 2; ++t) {
    gl_lds16(Ag + t * 32, As[t] + tid * 8);
    gl_lds16(Ag + t * 32 + (size_t)64 * DMODEL, As[t] + 2048 + tid * 8);
    gl_lds16(Bg + t * 32, Bs[t] + tid * 8);
  }

  for (int kt = 0; kt < 32; kt += 2) {
    __syncthreads();  // tiles kt,kt+1 landed; buffers (kt+2)&3,(kt+3)&3 are free
    if (kt < 30) {    // prefetch tiles kt+2, kt+3
#pragma unroll
      for (int t = 2; t < 4; ++t) {
        const int k0 = (kt + t) * 32;
        const int bsel = (kt + t) & 3;
        gl_lds16(Ag + k0, As[bsel] + tid * 8);
        gl_lds16(Ag + k0 + (size_t)64 * DMODEL, As[bsel] + 2048 + tid * 8);
        gl_lds16(Bg + k0, Bs[bsel] + tid * 8);
      }
    }
    const int ch = (q ^ kc) << 3;
#pragma unroll
    for (int ks = 0; ks < 2; ++ks) {
      const int cur = (kt + ks) & 3;
      bf16x8 af[4], bfr[2];
#pragma unroll
      for (int i = 0; i < 4; ++i)
        af[i] = *reinterpret_cast<const bf16x8*>(As[cur] + (wm * 64 + i * 16 + c) * 32 + ch);
#pragma unroll
      for (int j = 0; j < 2; ++j)
        bfr[j] = *reinterpret_cast<const bf16x8*>(Bs[cur] + (wn * 32 + j * 16 + c) * 32 + ch);
#pragma unroll
      for (int i = 0; i < 4; ++i)
#pragma unroll
        for (int j = 0; j < 2; ++j)
          acc[i][j] = __builtin_amdgcn_mfma_f32_16x16x32_bf16(af[i], bfr[j], acc[i][j], 0, 0, 0);
    }
  }

#pragma unroll
  for (int j = 0; j < 2; ++j) {
    const int gn = bn + wn * 32 + j * 16 + c;
    const float bv = bias[gn];
#pragma unroll
    for (int i = 0; i < 4; ++i)
#pragma unroll
      for (int r = 0; r < 4; ++r) {
        const int gm = bm + wm * 64 + i * 16 + q * 4 + r;
        C[(size_t)gm * DMODEL + gn] = acc[i][j][r] + bv;
      }
  }
}

extern "C" void kernel_launch(void* const* d_in, const int* in_sizes, int n_in,
                              void* d_out, int out_size, void* d_ws, size_t ws_size,
                              hipStream_t stream) {
  (void)in_sizes; (void)n_in; (void)out_size; (void)ws_size;
  const float* input = (const float*)d_in[0];
  // d_in[1] = causal mask, implemented analytically
  const float* W_qkv = (const float*)d_in[2];
  const float* b_qkv = (const float*)d_in[3];
  const float* W_out = (const float*)d_in[4];
  const float* b_out = (const float*)d_in[5];
  float* out = (float*)d_out;

  unsigned char* ws = (unsigned char*)d_ws;
  unsigned short* Abf   = (unsigned short*)(ws + 0);          // 8 MB; dead after GEMM1
  unsigned short* WqkvT = (unsigned short*)(ws + 8388608);    // 6 MB
  unsigned short* WoutT = (unsigned short*)(ws + 14680064);   // 2 MB
  unsigned short* Qbf   = (unsigned short*)(ws + 16777216);   // 8 MB [B,H,L,64] (pre-scaled)
  unsigned short* Kbf   = (unsigned short*)(ws + 25165824);   // 8 MB [B,H,L,64]
  unsigned short* VTbf  = (unsigned short*)(ws + 33554432);   // 8 MB [B,H,64,L] (direct from GEMM1)
  unsigned short* Aout  = (unsigned short*)(ws + 41943040);   // 8 MB [4096][1024]

  k_prepass<<<8192, 256, 0, stream>>>(input, Abf, W_qkv, WqkvT, W_out, WoutT);
  k_gemm_qkv<<<dim3(32, 24), 256, 0, stream>>>(Abf, WqkvT, b_qkv, out, Qbf, Kbf, VTbf);
  k_attn<<<1024, 256, 0, stream>>>(Qbf, Kbf, VTbf, Aout);
  k_gemm_out<<<dim3(32, 16), 256, 0, stream>>>(Aout, WoutT, b_out, out);
}

// Round 11
// 179.770 us; speedup vs baseline: 1.3841x; 1.0445x over previous
//
#include <hip/hip_runtime.h>
#include <cstdint>

#define NHEAD 16
#define DHEAD 64
#define SEQ   2048
#define DMODEL 1024
#define MTOT  4096
#define NQKV  3072

typedef __bf16 bf16x8 __attribute__((ext_vector_type(8)));
typedef short  s16x4  __attribute__((ext_vector_type(4)));
typedef float  f32x4  __attribute__((ext_vector_type(4)));

__device__ __forceinline__ unsigned short f2bf(float f) {
  union { float f; unsigned u; } v; v.f = f;
  unsigned r = v.u + 0x7fffu + ((v.u >> 16) & 1u);
  return (unsigned short)(r >> 16);
}

// async global->LDS, 16B per lane. LDS dest must be wave-uniform base + lane*16.
__device__ __forceinline__ void gl_lds16(const void* g, void* l) {
  __builtin_amdgcn_global_load_lds(
      reinterpret_cast<const __attribute__((address_space(1))) unsigned int*>(
          reinterpret_cast<uintptr_t>(g)),
      reinterpret_cast<__attribute__((address_space(3))) unsigned int*>(
          reinterpret_cast<uintptr_t>(l)),
      16, 0, 0);
}

#if __has_builtin(__builtin_amdgcn_mfma_f32_16x16x16bf16_1k)
#define MFMA_PV(a, b, c) __builtin_amdgcn_mfma_f32_16x16x16bf16_1k(a, b, c, 0, 0, 0)
#else
__device__ __forceinline__ f32x4 mfma_pv_asm(s16x4 a, s16x4 b, f32x4 c) {
  f32x4 d;
  asm volatile("v_mfma_f32_16x16x16_bf16 %0, %1, %2, %3"
               : "=v"(d) : "v"(a), "v"(b), "v"(c));
  return d;
}
#define MFMA_PV(a, b, c) mfma_pv_asm(a, b, c)
#endif

// Q pre-scale: softmax scale folded into Q at GEMM1 (0.125 * log2(e)).
#define QSCALE 0.18033688011112042f

// ---------------- merged pre-pass: fp32->bf16 input cvt + both weight transposes ----
__global__ void k_prepass(const float* __restrict__ x, unsigned short* __restrict__ y,
                          const float* __restrict__ W0, unsigned short* __restrict__ T0,
                          const float* __restrict__ W1, unsigned short* __restrict__ T1) {
  __shared__ unsigned short t[32][33];
  const int bid = blockIdx.x;
  if (bid < 4096) {
    const int i = bid * 256 + threadIdx.x;
    float4 v = reinterpret_cast<const float4*>(x)[i];
    ushort4 o;
    o.x = f2bf(v.x); o.y = f2bf(v.y); o.z = f2bf(v.z); o.w = f2bf(v.w);
    reinterpret_cast<ushort4*>(y)[i] = o;
  } else {
    const int b2 = bid - 4096;
    const int bx = b2 & 127;           // 0..127 (96 for W_qkv, 32 for W_out)
    const int by = b2 >> 7;            // 0..31  (K/32 tiles)
    const float* W = (bx < 96) ? W0 : W1;
    unsigned short* WT = (bx < 96) ? T0 : T1;
    const int N = (bx < 96) ? 3072 : 1024;
    const int n0 = ((bx < 96) ? bx : (bx - 96)) * 32;
    const int k0 = by * 32;
    const int tx = threadIdx.x & 31, ty = threadIdx.x >> 5;
    for (int i = ty; i < 32; i += 8)
      t[i][tx] = f2bf(W[(size_t)(k0 + i) * N + n0 + tx]);
    __syncthreads();
    for (int i = ty; i < 32; i += 8)
      WT[(size_t)(n0 + i) * 1024 + k0 + tx] = t[tx][i];
  }
}

// ---------------- GEMM1: double-buffered LDS, 1 barrier/iter, BK=32 ----------------
// R0-proven main loop; R3-proven fused V^T epilogue; QSCALE kept.
// R11: q/k bf16 epilogue stores now LDS-staged + coalesced (same pattern as the
// V^T and attn epilogues). Old path: 64 scalar ushort stores/wave at 50% line
// utilization (2x write amplification, +20MB). New: 64 ds_write_b16 (XOR-swizzled,
// conflict-free) + 8 fully-coalesced 16B global stores per wave.
__global__ __launch_bounds__(256, 3) void k_gemm_qkv(
    const unsigned short* __restrict__ A, const unsigned short* __restrict__ Bt,
    const float* __restrict__ bias, float* __restrict__ outbase,
    unsigned short* __restrict__ qbf, unsigned short* __restrict__ kbf,
    unsigned short* __restrict__ vtbf) {
  __shared__ __attribute__((aligned(16))) unsigned short As[2][128 * 32];
  __shared__ __attribute__((aligned(16))) unsigned short Bs[2][128 * 32];
  const int tid = threadIdx.x, lane = tid & 63;
  const int w = tid >> 6, wm = w >> 1, wn = w & 1;
  const int c = lane & 15, q = lane >> 4;
  const int kc = (c & 3) ^ ((c >> 2) & 3);        // frag-read swizzle key
  const int bm = blockIdx.x * 128, bn = blockIdx.y * 128;
  const int srow = tid >> 2;
  const int skey = (srow & 3) ^ ((srow >> 2) & 3);
  const int scolsw = (((tid & 3) ^ skey) << 3);   // swizzled global source column
  const unsigned short* Ag = A + (size_t)(bm + srow) * DMODEL + scolsw;
  const unsigned short* Bg = Bt + (size_t)(bn + srow) * DMODEL + scolsw;
  f32x4 acc[4][4] = {};

  // stage tile 0 into buf 0
  gl_lds16(Ag, As[0] + tid * 8);
  gl_lds16(Ag + (size_t)64 * DMODEL, As[0] + 2048 + tid * 8);
  gl_lds16(Bg, Bs[0] + tid * 8);
  gl_lds16(Bg + (size_t)64 * DMODEL, Bs[0] + 2048 + tid * 8);

  for (int kt = 0; kt < 32; ++kt) {
    const int cur = kt & 1;
    __syncthreads();  // drains loads issued LAST iter (fully latency-hidden)
    if (kt < 31) {    // prefetch tile kt+1 into the other buffer
      const int k0 = (kt + 1) * 32;
      gl_lds16(Ag + k0, As[cur ^ 1] + tid * 8);
      gl_lds16(Ag + k0 + (size_t)64 * DMODEL, As[cur ^ 1] + 2048 + tid * 8);
      gl_lds16(Bg + k0, Bs[cur ^ 1] + tid * 8);
      gl_lds16(Bg + k0 + (size_t)64 * DMODEL, Bs[cur ^ 1] + 2048 + tid * 8);
    }
    const int ch = (q ^ kc) << 3;
    bf16x8 af[4], bfr[4];
#pragma unroll
    for (int i = 0; i < 4; ++i)
      af[i] = *reinterpret_cast<const bf16x8*>(As[cur] + (wm * 64 + i * 16 + c) * 32 + ch);
#pragma unroll
    for (int j = 0; j < 4; ++j)
      bfr[j] = *reinterpret_cast<const bf16x8*>(Bs[cur] + (wn * 64 + j * 16 + c) * 32 + ch);
#pragma unroll
    for (int i = 0; i < 4; ++i)
#pragma unroll
      for (int j = 0; j < 4; ++j)
        acc[i][j] = __builtin_amdgcn_mfma_f32_16x16x32_bf16(af[i], bfr[j], acc[i][j], 0, 0, 0);
  }

  const int sec = bn >> 10;  // 0=q 1=k 2=v (block-uniform)
  __syncthreads();  // all waves done reading As/Bs -> reusable as staging (all secs)
  char* stg = reinterpret_cast<char*>((w < 2) ? (&As[0][0] + w * 4096)
                                              : (&Bs[0][0] + (w - 2) * 4096));
  const int gmb = bm + wm * 64;
  const int bb = gmb >> 11, tokb = gmb & 2047;   // constant per wave (64-run aligned)
  const int hh = ((bn + wn * 64) >> 6) & 15;     // constant per wave

  if (sec == 2) {
    // ---- V: fp32 copy direct + V^T bf16 via LDS-staged per-wave transpose ----
#pragma unroll
    for (int j = 0; j < 4; ++j) {
      const int gn = bn + wn * 64 + j * 16 + c;
      const float bv = bias[gn];
      const int cc = gn & 1023;
      const int ln = j * 16 + c;                 // local dd 0..63
#pragma unroll
      for (int i = 0; i < 4; ++i) {
        const int gm0 = bm + wm * 64 + i * 16 + q * 4;
        const int lm0 = i * 16 + q * 4;          // local tok 0..63 (4-run)
        float vals[4];
#pragma unroll
        for (int r = 0; r < 4; ++r) {
          vals[r] = acc[i][j][r] + bv;
          outbase[(size_t)8388608 + (size_t)(gm0 + r) * DMODEL + cc] = vals[r];
        }
        ushort4 tv;
        tv.x = f2bf(vals[0]); tv.y = f2bf(vals[1]);
        tv.z = f2bf(vals[2]); tv.w = f2bf(vals[3]);
        // staged layout: row ln (128B), byte offset (lm*2) XOR ((ln&7)<<4)
        *reinterpret_cast<ushort4*>(stg + ln * 128 + ((lm0 * 2) ^ ((ln & 7) << 4))) = tv;
      }
    }
    // readback (16B chunks, XOR-consistent) + coalesced V^T store
    unsigned short* vrow = vtbf + ((size_t)(bb * NHEAD + hh) * DHEAD) * SEQ + tokb;
#pragma unroll
    for (int it = 0; it < 8; ++it) {
      const int r_ = (lane >> 3) + it * 8;       // dd row 0..63
      const int g = lane & 7;                    // 16B chunk along tok
      const uint4 val = *reinterpret_cast<const uint4*>(
          stg + r_ * 128 + (((unsigned)g << 4) ^ ((r_ & 7) << 4)));
      *reinterpret_cast<uint4*>(vrow + (size_t)r_ * SEQ + g * 8) = val;
    }
  } else {
    // ---- q/k: fp32 copy (k only, already coalesced) + bf16 via LDS staging ----
    // staged layout: [tok][dd] rows of 128B; byte offset (dd*2) XOR key(tok),
    // key = ((tok>>2)&7)<<4 -> the 4 q-rows of each store group get distinct
    // 16B chunks -> 64 lanes spread over all 32 banks (2/bank, free).
#pragma unroll
    for (int j = 0; j < 4; ++j) {
      const int gn = bn + wn * 64 + j * 16 + c;
      const float bv = bias[gn];
      const int cc = gn & 1023;
      const int ld = j * 16 + c;                 // local dd 0..63
#pragma unroll
      for (int i = 0; i < 4; ++i) {
#pragma unroll
        for (int r = 0; r < 4; ++r) {
          const int gm = bm + wm * 64 + i * 16 + q * 4 + r;
          const int lt = i * 16 + q * 4 + r;     // local tok 0..63
          const float val = acc[i][j][r] + bv;
          if (sec == 1)
            outbase[(size_t)4194304 + (size_t)gm * DMODEL + cc] = val;
          const unsigned short bfv = (sec == 0) ? f2bf(val * QSCALE) : f2bf(val);
          *reinterpret_cast<unsigned short*>(
              stg + lt * 128 + ((ld * 2) ^ (((lt >> 2) & 7) << 4))) = bfv;
        }
      }
    }
    __builtin_amdgcn_s_waitcnt(0);  // lgkmcnt(0): own-wave ds_writes visible
    unsigned short* dst = (sec == 0 ? qbf : kbf) +
                          ((size_t)(bb * NHEAD + hh) * SEQ + tokb) * DHEAD;
#pragma unroll
    for (int it = 0; it < 8; ++it) {
      const int r_ = (lane >> 3) + it * 8;       // tok row 0..63
      const int g = lane & 7;                    // 16B chunk along dd
      const uint4 val = *reinterpret_cast<const uint4*>(
          stg + r_ * 128 + (((unsigned)g << 4) ^ ((((unsigned)r_ >> 2) & 7) << 4)));
      *reinterpret_cast<uint4*>(dst + (size_t)r_ * DHEAD + g * 8) = val;
    }
  }
}

// ---------------- flash attention (causal), S^T trick, 64-row Q tiles ----------------
// R9-proven (frozen): gl_lds16 single-buffer 2-barrier staging, no-max sum-exp
// softmax, pre-scaled Q, setprio, coalesced LDS-staged epilogue.
__global__ __launch_bounds__(256) void k_attn(
    const unsigned short* __restrict__ qbf, const unsigned short* __restrict__ kbf,
    const unsigned short* __restrict__ vtbf, unsigned short* __restrict__ aout) {
  __shared__ __attribute__((aligned(16))) unsigned short Ks[128 * 64];
  __shared__ __attribute__((aligned(16))) unsigned short Vs[64 * 128];

  const int tid = threadIdx.x, lane = tid & 63, w = tid >> 6;
  const int c = lane & 15, q = lane >> 4;
  const int oo = blockIdx.x >> 5, kk = oo & 7, ssl = oo >> 3;
  const int qsub = (ssl == 0) ? (31 - kk) : (ssl == 1) ? kk
                 : (ssl == 2) ? (23 - kk) : (8 + kk);
  const int bh = blockIdx.x & 31;
  const int kmax = qsub >> 1;
  const size_t hoff = (size_t)bh * SEQ * DHEAD;

  const unsigned short* qg = qbf + hoff + (size_t)(qsub * 64 + w * 16 + c) * DHEAD;
  const bf16x8 qb0 = *reinterpret_cast<const bf16x8*>(qg + q * 8);
  const bf16x8 qb1 = *reinterpret_cast<const bf16x8*>(qg + 32 + q * 8);

  f32x4 o[4] = {};
  float lpart = 0.f;  // per-lane partial denominator (reduced once at the end)
  const int qloc = (qsub & 1) * 64 + w * 16 + c;
  const int cx = c & 7;

  const int krow = tid >> 3, kswz = (tid & 7) ^ (krow & 7);
  const int vrow = tid >> 4, vswz = (tid & 15) ^ (vrow & 7);
  const unsigned short* kgb = kbf + hoff;
  const unsigned short* vgb = vtbf + (size_t)bh * DHEAD * SEQ;

  for (int kt = 0; kt <= kmax; ++kt) {
    __syncthreads();
    const unsigned short* kg = kgb + (size_t)kt * 128 * DHEAD;
#pragma unroll
    for (int is = 0; is < 4; ++is)
      gl_lds16(kg + (krow + is * 32) * 64 + kswz * 8, Ks + is * 2048 + tid * 8);
    const unsigned short* vg = vgb + kt * 128;
#pragma unroll
    for (int is = 0; is < 4; ++is)
      gl_lds16(vg + (size_t)(vrow + is * 16) * SEQ + vswz * 8, Vs + is * 2048 + tid * 8);
    __syncthreads();

    f32x4 s[8];
    __builtin_amdgcn_s_setprio(1);
#pragma unroll
    for (int mi = 0; mi < 8; ++mi) {
      const unsigned short* kr = Ks + (mi * 16 + c) * 64;
      const bf16x8 ak0 = *reinterpret_cast<const bf16x8*>(kr + (q ^ cx) * 8);
      const bf16x8 ak1 = *reinterpret_cast<const bf16x8*>(kr + ((4 + q) ^ cx) * 8);
      f32x4 t = {};
      t = __builtin_amdgcn_mfma_f32_16x16x32_bf16(ak0, qb0, t, 0, 0, 0);
      t = __builtin_amdgcn_mfma_f32_16x16x32_bf16(ak1, qb1, t, 0, 0, 0);
      s[mi] = t;
    }
    __builtin_amdgcn_s_setprio(0);

    if (kt == kmax) {
#pragma unroll
      for (int mi = 0; mi < 8; ++mi)
#pragma unroll
        for (int r = 0; r < 4; ++r)
          if (mi * 16 + q * 4 + r > qloc) s[mi][r] = -__builtin_inff();
    }

    s16x4 pb[8];
#pragma unroll
    for (int mi = 0; mi < 8; ++mi) {
      const float p0 = __builtin_amdgcn_exp2f(s[mi][0]);
      const float p1 = __builtin_amdgcn_exp2f(s[mi][1]);
      const float p2 = __builtin_amdgcn_exp2f(s[mi][2]);
      const float p3 = __builtin_amdgcn_exp2f(s[mi][3]);
      lpart += (p0 + p1) + (p2 + p3);
      union { s16x4 v; unsigned u[2]; } pk;
      pk.u[0] = __builtin_amdgcn_perm(__float_as_uint(p1), __float_as_uint(p0), 0x07060302u);
      pk.u[1] = __builtin_amdgcn_perm(__float_as_uint(p3), __float_as_uint(p2), 0x07060302u);
      pb[mi] = pk.v;
    }

    __builtin_amdgcn_s_setprio(1);
#pragma unroll
    for (int dm = 0; dm < 4; ++dm) {
      const unsigned short* vr = Vs + (dm * 16 + c) * 128 + (q & 1) * 4;
#pragma unroll
      for (int kf = 0; kf < 8; ++kf) {
        const s16x4 av = *reinterpret_cast<const s16x4*>(
            vr + (((kf * 2 + (q >> 1)) ^ cx) * 8));
        o[dm] = MFMA_PV(av, pb[kf], o[dm]);
      }
    }
    __builtin_amdgcn_s_setprio(0);
  }

  // final denominator reduce (q-groups hold disjoint k-slices of the same q-row)
  float lrun = lpart;
  lrun += __shfl_xor(lrun, 16);
  lrun += __shfl_xor(lrun, 32);

  __syncthreads();  // all waves done reading Ks -> safe to reuse as staging

  // ---- coalesced epilogue (R2-proven) ----
  const float linv = 1.0f / lrun;
  unsigned short* Ws = Ks + w * 1024;  // 2KB per wave, disjoint regions
#pragma unroll
  for (int dm = 0; dm < 4; ++dm) {
    ushort4 ov;
    ov.x = f2bf(o[dm][0] * linv);
    ov.y = f2bf(o[dm][1] * linv);
    ov.z = f2bf(o[dm][2] * linv);
    ov.w = f2bf(o[dm][3] * linv);
    const int bofs = c * 128 + ((dm * 32 + q * 8) ^ ((c & 7) << 4));  // bytes
    *reinterpret_cast<ushort4*>(Ws + (bofs >> 1)) = ov;
  }
  const int b = bh >> 4, h = bh & 15;
#pragma unroll
  for (int it = 0; it < 2; ++it) {
    const int r_ = (lane >> 3) + it * 8;
    const int g = lane & 7;
    const uint4 val = *reinterpret_cast<const uint4*>(
        Ws + ((r_ * 128 + (((unsigned)g ^ (r_ & 7)) << 4)) >> 1));
    const int row = b * SEQ + qsub * 64 + w * 16 + r_;
    *reinterpret_cast<uint4*>(aout + (size_t)row * DMODEL + h * 64 + g * 8) = val;
  }
}

// ---------------- GEMM2: 128x64 tiles, QUAD-buffered, BK=32 (R10-proven) ----------
__global__ __launch_bounds__(256) void k_gemm_out(
    const unsigned short* __restrict__ A, const unsigned short* __restrict__ Bt,
    const float* __restrict__ bias, float* __restrict__ C) {
  __shared__ __attribute__((aligned(16))) unsigned short As[4][128 * 32];
  __shared__ __attribute__((aligned(16))) unsigned short Bs[4][64 * 32];
  const int tid = threadIdx.x, lane = tid & 63;
  const int w = tid >> 6, wm = w >> 1, wn = w & 1;
  const int c = lane & 15, q = lane >> 4;
  const int kc = (c & 3) ^ ((c >> 2) & 3);
  const int bm = blockIdx.x * 128, bn = blockIdx.y * 64;
  const int srow = tid >> 2;
  const int skey = (srow & 3) ^ ((srow >> 2) & 3);
  const int scolsw = (((tid & 3) ^ skey) << 3);
  const unsigned short* Ag = A + (size_t)(bm + srow) * DMODEL + scolsw;
  const unsigned short* Bg = Bt + (size_t)(bn + srow) * DMODEL + scolsw;
  f32x4 acc[4][2] = {};

  // stage tiles 0,1 into buffers 0,1
#pragma unroll
  for (int t = 0; t < 2; ++t) {
    gl_lds16(Ag + t * 32, As[t] + tid * 8);
    gl_lds16(Ag + t * 32 + (size_t)64 * DMODEL, As[t] + 2048 + tid * 8);
    gl_lds16(Bg + t * 32, Bs[t] + tid * 8);
  }

  for (int kt = 0; kt < 32; kt += 2) {
    __syncthreads();  // tiles kt,kt+1 landed; buffers (kt+2)&3,(kt+3)&3 are free
    if (kt < 30) {    // prefetch tiles kt+2, kt+3
#pragma unroll
      for (int t = 2; t < 4; ++t) {
        const int k0 = (kt + t) * 32;
        const int bsel = (kt + t) & 3;
        gl_lds16(Ag + k0, As[bsel] + tid * 8);
        gl_lds16(Ag + k0 + (size_t)64 * DMODEL, As[bsel] + 2048 + tid * 8);
        gl_lds16(Bg + k0, Bs[bsel] + tid * 8);
      }
    }
    const int ch = (q ^ kc) << 3;
#pragma unroll
    for (int ks = 0; ks < 2; ++ks) {
      const int cur = (kt + ks) & 3;
      bf16x8 af[4], bfr[2];
#pragma unroll
      for (int i = 0; i < 4; ++i)
        af[i] = *reinterpret_cast<const bf16x8*>(As[cur] + (wm * 64 + i * 16 + c) * 32 + ch);
#pragma unroll
      for (int j = 0; j < 2; ++j)
        bfr[j] = *reinterpret_cast<const bf16x8*>(Bs[cur] + (wn * 32 + j * 16 + c) * 32 + ch);
#pragma unroll
      for (int i = 0; i < 4; ++i)
#pragma unroll
        for (int j = 0; j < 2; ++j)
          acc[i][j] = __builtin_amdgcn_mfma_f32_16x16x32_bf16(af[i], bfr[j], acc[i][j], 0, 0, 0);
    }
  }

#pragma unroll
  for (int j = 0; j < 2; ++j) {
    const int gn = bn + wn * 32 + j * 16 + c;
    const float bv = bias[gn];
#pragma unroll
    for (int i = 0; i < 4; ++i)
#pragma unroll
      for (int r = 0; r < 4; ++r) {
        const int gm = bm + wm * 64 + i * 16 + q * 4 + r;
        C[(size_t)gm * DMODEL + gn] = acc[i][j][r] + bv;
      }
  }
}

extern "C" void kernel_launch(void* const* d_in, const int* in_sizes, int n_in,
                              void* d_out, int out_size, void* d_ws, size_t ws_size,
                              hipStream_t stream) {
  (void)in_sizes; (void)n_in; (void)out_size; (void)ws_size;
  const float* input = (const float*)d_in[0];
  // d_in[1] = causal mask, implemented analytically
  const float* W_qkv = (const float*)d_in[2];
  const float* b_qkv = (const float*)d_in[3];
  const float* W_out = (const float*)d_in[4];
  const float* b_out = (const float*)d_in[5];
  float* out = (float*)d_out;

  unsigned char* ws = (unsigned char*)d_ws;
  unsigned short* Abf   = (unsigned short*)(ws + 0);          // 8 MB; dead after GEMM1
  unsigned short* WqkvT = (unsigned short*)(ws + 8388608);    // 6 MB
  unsigned short* WoutT = (unsigned short*)(ws + 14680064);   // 2 MB
  unsigned short* Qbf   = (unsigned short*)(ws + 16777216);   // 8 MB [B,H,L,64] (pre-scaled)
  unsigned short* Kbf   = (unsigned short*)(ws + 25165824);   // 8 MB [B,H,L,64]
  unsigned short* VTbf  = (unsigned short*)(ws + 33554432);   // 8 MB [B,H,64,L] (direct from GEMM1)
  unsigned short* Aout  = (unsigned short*)(ws + 41943040);   // 8 MB [4096][1024]

  k_prepass<<<8192, 256, 0, stream>>>(input, Abf, W_qkv, WqkvT, W_out, WoutT);
  k_gemm_qkv<<<dim3(32, 24), 256, 0, stream>>>(Abf, WqkvT, b_qkv, out, Qbf, Kbf, VTbf);
  k_attn<<<1024, 256, 0, stream>>>(Qbf, Kbf, VTbf, Aout);
  k_gemm_out<<<dim3(32, 16), 256, 0, stream>>>(Aout, WoutT, b_out, out);
}